// Round 15
// baseline (359.306 us; speedup 1.0000x reference)
//
#include <hip/hip_runtime.h>

typedef float vf4 __attribute__((ext_vector_type(4)));
typedef float f32x4 __attribute__((ext_vector_type(4)));
typedef short short8 __attribute__((ext_vector_type(8)));
typedef unsigned int u32;
typedef u32 u32x4 __attribute__((ext_vector_type(4)));

// ======================================================================
// Compile-time CG table (validated rounds 1-14): real-SH CG build in
// fp64 via constexpr. Coefficients fold to literals; zeros DCE away.
// ======================================================================
namespace cgc {

struct FTab { double f[13]; };
constexpr FTab mkft(){ FTab t{}; t.f[0]=1.0; for(int i=1;i<13;i++) t.f[i]=t.f[i-1]*i; return t; }
constexpr FTab FTB = mkft();

constexpr double csqrt(double x){
  double g = x < 1.0 ? 1.0 : x;
  for(int i=0;i<40;i++) g = 0.5*(g + x/g);
  return g;
}

constexpr double cgcoef(int j1,int m1,int j2,int m2,int j3,int m3){
  if (m1+m2 != m3) return 0.0;
  double pref = csqrt((double)(2*j3+1) * FTB.f[j3+j1-j2] * FTB.f[j3-j1+j2]
                      * FTB.f[j1+j2-j3] / FTB.f[j1+j2+j3+1]);
  pref *= csqrt(FTB.f[j3+m3]*FTB.f[j3-m3]*FTB.f[j1-m1]*FTB.f[j1+m1]
                *FTB.f[j2-m2]*FTB.f[j2+m2]);
  double s = 0.0;
  for(int k=0;k<=j1+j2-j3;k++){
    int e1=j1+j2-j3-k, e2=j1-m1-k, e3=j2+m2-k, e4=j3-j2+m1+k, e5=j3-j1-m2+k;
    if (e1<0||e2<0||e3<0||e4<0||e5<0) continue;
    double prod = FTB.f[k]*FTB.f[e1]*FTB.f[e2]*FTB.f[e3]*FTB.f[e4]*FTB.f[e5];
    s += (k&1) ? (-1.0/prod) : (1.0/prod);
  }
  return pref*s;
}

struct Tab { double v[11][125]; };

constexpr Tab build(){
  Tab T{};
  constexpr int PL1[11]={0,0,0,1,1,1,1,2,2,2,2};
  constexpr int PL2[11]={0,1,2,0,1,1,2,0,1,2,2};
  constexpr int PL3[11]={0,1,2,1,0,2,1,2,1,0,2};
  constexpr int NOUT[3]={3,4,4};
  double qr[3][5][5]{}, qi[3][5][5]{};
  for(int l=0;l<3;l++){
    const double is2 = 0.70710678118654752440;
    for(int m=-l;m<0;m++){ qr[l][l+m][l-m]=is2; qi[l][l+m][l+m]=-is2; }
    qr[l][l][l]=1.0;
    for(int m=1;m<=l;m++){ double sg=(m&1)?-1.0:1.0; qr[l][l+m][l+m]=sg*is2; qi[l][l+m][l-m]=sg*is2; }
    if (l==1){ for(int a=0;a<5;a++)for(int b=0;b<5;b++){ double re=qr[1][a][b], im=qi[1][a][b]; qr[1][a][b]=im; qi[1][a][b]=-re; } }
    if (l==2){ for(int a=0;a<5;a++)for(int b=0;b<5;b++){ qr[2][a][b]=-qr[2][a][b]; qi[2][a][b]=-qi[2][a][b]; } }
  }
  for(int p=0;p<11;p++){
    int l1=PL1[p], l2=PL2[p], l3=PL3[p];
    int d1=2*l1+1, d2=2*l2+1, d3=2*l3+1;
    double cs[125]{};
    for(int i=0;i<d1;i++)for(int k=0;k<d2;k++)for(int m=0;m<d3;m++)
      cs[(i*d2+k)*d3+m] = cgcoef(l1,i-l1,l2,k-l2,l3,m-l3);
    double nrm2 = 0.0;
    for(int j=0;j<d1;j++)for(int lc=0;lc<d2;lc++)for(int n=0;n<d3;n++){
      double ar = 0.0;
      for(int i=0;i<d1;i++){
        double q1r=qr[l1][i][j], q1i=qi[l1][i][j];
        if (q1r==0.0 && q1i==0.0) continue;
        for(int k=0;k<d2;k++){
          double q2r=qr[l2][k][lc], q2i=qi[l2][k][lc];
          if (q2r==0.0 && q2i==0.0) continue;
          double abr=q1r*q2r-q1i*q2i, abi=q1r*q2i+q1i*q2r;
          for(int m=0;m<d3;m++){
            double c=cs[(i*d2+k)*d3+m];
            if (c==0.0) continue;
            double q3r=qr[l3][m][n], q3i=-qi[l3][m][n];   // conj(q3)
            ar += (abr*q3r - abi*q3i)*c;
          }
        }
      }
      T.v[p][(j*d2+lc)*d3+n] = ar;
      nrm2 += ar*ar;
    }
    double sc = csqrt((double)(2*l3+1)/(double)NOUT[l3]) / csqrt(nrm2);
    for(int e=0;e<d1*d2*d3;e++) T.v[p][e] *= sc;
  }
  return T;
}

constexpr Tab CGT = build();

} // namespace cgc

// ======================================================================
// Sparse per-path TP: coefficients are literals, zeros DCE'd.
// ======================================================================
template<int P,int L1,int L2,int L3>
__device__ __forceinline__ void tp_path(float wp, const float (&xi)[9],
                                        const float (&yi)[9], float (&o)[9])
{
  constexpr int D1=2*L1+1, D2=2*L2+1, D3=2*L3+1, O1=L1*L1, O2=L2*L2, O3=L3*L3;
  float z[D3];
#pragma unroll
  for(int k=0;k<D3;k++) z[k]=0.f;
#pragma unroll
  for(int i=0;i<D1;i++){
#pragma unroll
    for(int j=0;j<D2;j++){
      const float tt = xi[O1+i]*yi[O2+j];
#pragma unroll
      for(int k=0;k<D3;k++){
        const double cv = cgc::CGT.v[P][(i*D2+j)*D3+k];
        if (cv > 1e-12 || cv < -1e-12)
          z[k] = fmaf((float)cv, tt, z[k]);
      }
    }
  }
#pragma unroll
  for(int k=0;k<D3;k++) o[O3+k] = fmaf(wp, z[k], o[O3+k]);
}

struct Vec9 { vf4 a, b; float s; };

// ---- exact 2-limb bf16 split, register-only packing ----
__device__ __forceinline__ void split8(const float (&a)[8],
                                       short8& hi8, short8& lo8)
{
  u32 hh[4], ll[4];
#pragma unroll
  for (int i = 0; i < 4; i++){
    const u32 u0 = __builtin_bit_cast(u32, a[2*i]);
    const u32 u1 = __builtin_bit_cast(u32, a[2*i+1]);
    const u32 t0 = u0 & 0xFFFF0000u;
    const u32 t1 = u1 & 0xFFFF0000u;
    hh[i] = (u0 >> 16) | t1;
    const float lo0 = a[2*i]   - __builtin_bit_cast(float, t0);
    const float lo1 = a[2*i+1] - __builtin_bit_cast(float, t1);
    ll[i] = (__builtin_bit_cast(u32, lo0) >> 16)
          | (__builtin_bit_cast(u32, lo1) & 0xFFFF0000u);
  }
  const u32x4 hv = { hh[0], hh[1], hh[2], hh[3] };
  const u32x4 lv = { ll[0], ll[1], ll[2], ll[3] };
  hi8 = __builtin_bit_cast(short8, hv);
  lo8 = __builtin_bit_cast(short8, lv);
}

// ======================================================================
// MFMA linear + fused TP, with runtime D-layout PROBE:
//  P1: A=1, B-elems=lane&15  -> D[m][n]=32n  (layout-invariant)
//  P2: A-elems=lane&15, B=1  -> D[m][n]=32m
//  lane1/reg0: (32,0) -> col=lane&15 ("guide"); (0,32) -> row=lane&15
//  ("swapped"); else scalar fallback. Write indices selected by mode.
// ======================================================================
#define NTILE 4

__global__ __launch_bounds__(256, 3) void e3_tp_kernel(
    const float* __restrict__ x, const float* __restrict__ y,
    const float* __restrict__ dist, const float* __restrict__ Wl,
    const float* __restrict__ bias, float* __restrict__ out)
{
  __shared__ float WV[32*388];           // [b=32][c*12+pad], 49664 B

  const int t = threadIdx.x;
  const int lane = t & 63;
  const int wv = t >> 6;
  const int bhalf = wv & 1, kbase = (wv >> 1) * 11;
  const int l15 = lane & 15, l4 = lane >> 4;
  const int c31 = t & 31, g8 = t >> 5;

  // ---- layout probe (wave-uniform result) ----
  int mode;
  {
    const u32x4 onev = {0x3F803F80u, 0x3F803F80u, 0x3F803F80u, 0x3F803F80u};
    const short8 ones8 = __builtin_bit_cast(short8, onev);
    const u32 lb = __builtin_bit_cast(u32, (float)l15);
    const u32 lp = (lb >> 16) | (lb & 0xFFFF0000u);
    const u32x4 lvv = { lp, lp, lp, lp };
    const short8 lane8 = __builtin_bit_cast(short8, lvv);
    f32x4 zz = {0.f,0.f,0.f,0.f};
    f32x4 p1 = __builtin_amdgcn_mfma_f32_16x16x32_bf16(ones8, lane8, zz, 0,0,0);
    f32x4 p2 = __builtin_amdgcn_mfma_f32_16x16x32_bf16(lane8, ones8, zz, 0,0,0);
    const float s1 = __shfl(p1[0], 1);
    const float s2 = __shfl(p2[0], 1);
    if      (s1 == 32.0f && s2 == 0.0f)  mode = 0;   // D col = lane&15
    else if (s1 == 0.0f  && s2 == 32.0f) mode = 1;   // D row = lane&15
    else                                 mode = 2;   // unknown -> scalar
  }

  auto ldv9 = [](const float* p) {
    Vec9 v;
    __builtin_memcpy(&v.a, p,   16);
    __builtin_memcpy(&v.b, p+4, 16);
    v.s = p[8];
    return v;
  };

  auto tpstore = [&](const Vec9& xv, const Vec9& yv,
                     const float (&wr)[11], float* o0) {
    const float xi[9] = {xv.a.x,xv.a.y,xv.a.z,xv.a.w,
                         xv.b.x,xv.b.y,xv.b.z,xv.b.w, xv.s};
    const float yi[9] = {yv.a.x,yv.a.y,yv.a.z,yv.a.w,
                         yv.b.x,yv.b.y,yv.b.z,yv.b.w, yv.s};
    float o[9];
#pragma unroll
    for (int k = 0; k < 9; k++) o[k] = 0.f;
    tp_path<0, 0,0,0>(wr[0],  xi, yi, o);
    tp_path<1, 0,1,1>(wr[1],  xi, yi, o);
    tp_path<2, 0,2,2>(wr[2],  xi, yi, o);
    tp_path<3, 1,0,1>(wr[3],  xi, yi, o);
    tp_path<4, 1,1,0>(wr[4],  xi, yi, o);
    tp_path<5, 1,1,2>(wr[5],  xi, yi, o);
    tp_path<6, 1,2,1>(wr[6],  xi, yi, o);
    tp_path<7, 2,0,2>(wr[7],  xi, yi, o);
    tp_path<8, 2,1,1>(wr[8],  xi, yi, o);
    tp_path<9, 2,2,0>(wr[9],  xi, yi, o);
    tp_path<10,2,2,2>(wr[10], xi, yi, o);
    vf4 s0 = { o[0], o[1], o[2], o[3] };
    vf4 s1 = { o[4], o[5], o[6], o[7] };
    __builtin_memcpy(o0,     &s0, 16);
    __builtin_memcpy(o0 + 4, &s1, 16);
    o0[8] = o[8];
  };

#pragma unroll 1
  for (int tile = 0; tile < NTILE; tile++){
    const int b0t = (blockIdx.x*NTILE + tile)*32;

    if (mode < 2) {
      // ---- MFMA phase: w[b][cp] = dist[b][:] @ W[:][cp] + bias[cp] ----
      float av[8];
      {
        const float* ap = dist + (long)(b0t + bhalf*16 + l15)*32 + l4*8;
        vf4 A0, A1;
        __builtin_memcpy(&A0, ap,   16);
        __builtin_memcpy(&A1, ap+4, 16);
        av[0]=A0.x; av[1]=A0.y; av[2]=A0.z; av[3]=A0.w;
        av[4]=A1.x; av[5]=A1.y; av[6]=A1.z; av[7]=A1.w;
      }
      short8 ahi, alo;
      split8(av, ahi, alo);

#pragma unroll
      for (int k = 0; k < 11; k++){
        const int cpcol = (kbase + k)*16;
        float bv8[8];
        const float* wp = Wl + (l4*8)*352 + cpcol + l15;
#pragma unroll
        for (int j = 0; j < 8; j++) bv8[j] = wp[j*352];
        short8 bhi, blo;
        split8(bv8, bhi, blo);

        f32x4 acc = {0.f, 0.f, 0.f, 0.f};
        acc = __builtin_amdgcn_mfma_f32_16x16x32_bf16(alo, blo, acc, 0,0,0);
        acc = __builtin_amdgcn_mfma_f32_16x16x32_bf16(ahi, blo, acc, 0,0,0);
        acc = __builtin_amdgcn_mfma_f32_16x16x32_bf16(alo, bhi, acc, 0,0,0);
        acc = __builtin_amdgcn_mfma_f32_16x16x32_bf16(ahi, bhi, acc, 0,0,0);

#pragma unroll
        for (int r = 0; r < 4; r++){
          const int row_r = bhalf*16 + ((mode == 0) ? (l4*4 + r) : l15);
          const int cp_r  = cpcol + ((mode == 0) ? l15 : (l4*4 + r));
          const int cc = (cp_r*373) >> 12;       // cp/11, exact for cp<352
          const int pp = cp_r - cc*11;
          WV[row_r*388 + cc*12 + pp] = acc[r] + bias[cp_r];
        }
      }
    } else {
      // ---- scalar fallback (layout unknown): 44 (b,cp) pairs/thread ----
      for (int i = t; i < 32*352; i += 256){
        const int b = i / 352, cp = i - b*352;
        float a = bias[cp];
        const float* dp = dist + (long)(b0t + b)*32;
#pragma unroll 8
        for (int f = 0; f < 32; f++) a = fmaf(dp[f], Wl[f*352 + cp], a);
        const int cc = (cp*373) >> 12, pp = cp - cc*11;
        WV[b*388 + cc*12 + pp] = a;
      }
    }
    __syncthreads();                             // w tile ready

    // ---- TP phase: 4 items/thread, fp32 w from LDS ----
    {
      const long rowbase = (long)b0t + g8*4;
      const float* xp = x   + rowbase*288 + c31*9;
      const float* yp = y   + rowbase*288 + c31*9;
      float*       op = out + rowbase*288 + c31*9;

#pragma unroll
      for (int r = 0; r < 4; r++){
        const float* wsrc = WV + (g8*4 + r)*388 + c31*12;
        vf4 wa, wb, wc;
        __builtin_memcpy(&wa, wsrc,   16);
        __builtin_memcpy(&wb, wsrc+4, 16);
        __builtin_memcpy(&wc, wsrc+8, 16);
        const float wr[11] = {wa.x,wa.y,wa.z,wa.w, wb.x,wb.y,wb.z,wb.w,
                              wc.x,wc.y,wc.z};
        Vec9 xv = ldv9(xp + r*288);
        Vec9 yv = ldv9(yp + r*288);
        tpstore(xv, yv, wr, op + r*288);
      }
    }
    __syncthreads();                             // TP reads done
  }
}

extern "C" void kernel_launch(void* const* d_in, const int* in_sizes, int n_in,
                              void* d_out, int out_size, void* d_ws, size_t ws_size,
                              hipStream_t stream)
{
  const float* x    = (const float*)d_in[0];
  const float* y    = (const float*)d_in[1];
  const float* dist = (const float*)d_in[2];
  const float* Wl   = (const float*)d_in[3];
  const float* bl   = (const float*)d_in[4];
  float* out = (float*)d_out;

  const int B = in_sizes[2] / 32;              // 131072 rows
  const int nblocks = B / (32*NTILE);          // 1024 blocks
  hipLaunchKernelGGL(e3_tp_kernel, dim3(nblocks), dim3(256), 0, stream,
                     x, y, dist, Wl, bl, out);
}